// Round 16
// baseline (728.208 us; speedup 1.0000x reference)
//
#include <hip/hip_runtime.h>

#define NROWS 65536
#define KC    1024
#define DD    256
#define ND    (NROWS*DD)      /* 16777216 */
#define KD    (KC*DD)         /* 262144 */
#define BROWS 64              /* rows per screen block */
#define CAP   24              /* LDS candidate list capacity per row */
#define CEXP  12              /* exported (filtered) candidates per row */
#define MARGIN 3.0f           /* >=2E for bf16-screen vs exact-replica (~14 sigma) */

/* output offsets (floats), concatenated in reference return order */
#define O_ZQ   0
#define O_DIST ND
#define O_IDX  (ND+1)
#define O_EMB  (ND+1+NROWS)
#define O_MT   (O_EMB+KD)
#define O_NT   (O_MT+KD)

/* ws float offsets */
#define WS_WSQ   0
#define WS_WPK   KC                    /* 131072 floats = 512KB bf16 W frags */
#define WS_ROWC  (KC+131072)           /* NROWS ints */
#define WS_BUCK  (WS_ROWC+NROWS)       /* NROWS ints */
#define WS_OFFS  (WS_BUCK+NROWS)       /* 1028 ints (1025 used) */
#define WS_POS   (WS_OFFS+1028)        /* KC ints */
#define WS_CNT   (WS_POS+KC)           /* KC ints */
#define WS_DIST  (WS_CNT+KC)           /* 1 float + 3 pad (legacy slot) */
#define WS_ST    (WS_DIST+4)           /* KD floats */
#define WS_CAND  (WS_ST+KD)            /* NROWS*CEXP u16 */
#define WS_SEL   (WS_CAND+NROWS*CEXP/2)/* NROWS u16 -> NROWS/2 floats */
#define WS_DISTP (WS_SEL+NROWS/2)      /* 512 floats: per-block dist partials */

typedef __attribute__((ext_vector_type(8))) short bf16x8;
typedef __attribute__((ext_vector_type(4))) float f32x4;

/* ===== exact-replica arithmetic contract (validated rounds 5-15) =====
   ref dist d2[r][c] = fadd( fsub( zsq[r], fmul(2, dot) ), wsq[c] )
   dot  = sequential ascending-k, SEPARATE mul+add roundings, single acc
   zsq/wsq = strict sequential sum of squares (mul+add, ascending)
   argmin  = first occurrence of min.
   Screen = bf16 MFMA (row-constant zsq dropped, absorbed in MARGIN);
   every code within MARGIN of the row's global screen min is rescored
   with the exact chain.  Decision kernels are round-15 VERBATIM; this
   round only (a) folds the zq epilogue into chunksum, (b) replaces the
   single-address dist atomic with per-block partials, (c) raises screen
   occupancy via launch_bounds. */

static __device__ __forceinline__ void minmerge(float& bv, int& bi, float ov, int oi){
  if (ov < bv || (ov == bv && oi < bi)) { bv = ov; bi = oi; }
}

static __device__ __forceinline__ unsigned short f2bf(float f){
  unsigned u = __float_as_uint(f);
  unsigned r = (u + 0x7FFFu + ((u>>16)&1u)) >> 16;   /* RNE */
  return (unsigned short)r;
}
static __device__ __forceinline__ bf16x8 cvt8(float4 a, float4 b){
  bf16x8 v;
  v[0]=(short)f2bf(a.x); v[1]=(short)f2bf(a.y); v[2]=(short)f2bf(a.z); v[3]=(short)f2bf(a.w);
  v[4]=(short)f2bf(b.x); v[5]=(short)f2bf(b.y); v[6]=(short)f2bf(b.z); v[7]=(short)f2bf(b.w);
  return v;
}

/* prologue: one wave per code. Lanes 0-31 pack bf16 B-fragments,
   lane 32 runs the exact wsq chain (scalar, round-11 verbatim). */
__global__ __launch_bounds__(256,1) void vq_prep_kernel(const float* __restrict__ W,
                                                        float* __restrict__ wsq,
                                                        bf16x8* __restrict__ wpk){
  const int wv = threadIdx.x>>6, lane = threadIdx.x&63;
  const int k = blockIdx.x*4 + wv;
  const float* wr = W + (size_t)k*DD;
  if (lane < 32){
    float4 x = *(const float4*)(wr + lane*8);
    float4 y = *(const float4*)(wr + lane*8 + 4);
    wpk[((k>>4)*8 + (lane>>2))*64 + (k&15) + 16*(lane&3)] = cvt8(x,y);
  } else if (lane == 32){
    float s = __fmul_rn(wr[0], wr[0]);
    for (int i=1;i<256;i++) s = __fadd_rn(s, __fmul_rn(wr[i], wr[i]));
    wsq[k] = s;
  }
}

/* screenA: 512 thr = 8 waves (2 row-groups x 4 col-groups), 64 rows x 1024
   codes per block, 1024 blocks, 3 blocks/CU (LDS 50.5KB x3 <= 160KB). */
__global__ __launch_bounds__(512,6) void vq_screen_kernel(
    const float* __restrict__ ze, const bf16x8* __restrict__ wpk,
    const float* __restrict__ wsq,
    unsigned short* __restrict__ cand, unsigned short* __restrict__ selw)
{
  __shared__ bf16x8 apkS[2048];        /* 32 KB: A fragments, linear */
  __shared__ float  wsqS[KC];          /* 4 KB */
  __shared__ float  gminW[8][BROWS];   /* 2 KB */
  __shared__ int    cntS[BROWS];
  __shared__ float  listV[BROWS][CAP]; /* 6 KB */
  __shared__ int    listI[BROWS][CAP]; /* 6 KB */

  const int tid = threadIdx.x;
  const int blk = blockIdx.x;
  const float* zb = ze + (size_t)blk*BROWS*DD;

  /* ---- phase 1: convert z tile to A fragments + init ---- */
  #pragma unroll
  for (int it=0; it<4; ++it){
    const int g  = it*512 + tid;
    const int r  = g >> 5;
    const int kb = g & 31;
    float4 a = *(const float4*)&zb[(size_t)r*DD + kb*8];
    float4 b = *(const float4*)&zb[(size_t)r*DD + kb*8 + 4];
    apkS[((r>>4)*8 + (kb>>2))*64 + (r&15) + 16*(kb&3)] = cvt8(a,b);
  }
  wsqS[tid]     = wsq[tid];
  wsqS[tid+512] = wsq[tid+512];
  if (tid < BROWS) cntS[tid] = 0;
  __syncthreads();

  /* ---- phase 2: MFMA screen + per-group min + candidate collection ---- */
  const int lane = tid & 63;
  const int wv   = tid >> 6;
  const int rg   = wv >> 2;
  const int cg   = wv & 3;

  #pragma unroll
  for (int p=0; p<2; ++p){
    f32x4 acc[2][8];
    #pragma unroll
    for (int mt=0; mt<2; ++mt)
      #pragma unroll
      for (int nt=0; nt<8; ++nt)
        acc[mt][nt] = (f32x4){0.f,0.f,0.f,0.f};

    #pragma unroll
    for (int s=0; s<8; ++s){
      bf16x8 af[2], bf[8];
      #pragma unroll
      for (int mt=0; mt<2; ++mt)
        af[mt] = apkS[((rg*2+mt)*8 + s)*64 + lane];
      #pragma unroll
      for (int nt=0; nt<8; ++nt)
        bf[nt] = wpk[(size_t)(((cg*16 + p*8 + nt)*8 + s)*64 + lane)];
      #pragma unroll
      for (int mt=0; mt<2; ++mt)
        #pragma unroll
        for (int nt=0; nt<8; ++nt)
          acc[mt][nt] = __builtin_amdgcn_mfma_f32_16x16x32_bf16(af[mt], bf[nt], acc[mt][nt], 0,0,0);
    }

    /* screen value = wsq - 2*dot (row-constant zsq dropped) */
    #pragma unroll
    for (int mt=0; mt<2; ++mt){
      #pragma unroll
      for (int r=0; r<4; ++r){
        const int row = rg*32 + mt*16 + (lane>>4)*4 + r;
        float dv[8]; float mn = 3.4e38f;
        #pragma unroll
        for (int nt=0; nt<8; ++nt){
          const int col = (cg*16 + p*8 + nt)*16 + (lane&15);
          dv[nt] = __fsub_rn(wsqS[col], __fmul_rn(2.0f, acc[mt][nt][r]));
          mn = fminf(mn, dv[nt]);
        }
        #pragma unroll
        for (int m=1; m<16; m<<=1) mn = fminf(mn, __shfl_xor(mn, m));
        if ((lane & 15) == 0) gminW[p*4+cg][row] = mn;
        const float thr = mn + MARGIN;
        #pragma unroll
        for (int nt=0; nt<8; ++nt){
          if (dv[nt] <= thr){
            int slot = atomicAdd(&cntS[row], 1);
            if (slot < CAP){
              listV[row][slot] = dv[nt];
              listI[row][slot] = (cg*16 + p*8 + nt)*16 + (lane&15);
            }
          }
        }
      }
    }
  }
  __syncthreads();

  /* ---- phase 3': global-min filter + export ---- */
  if (tid < BROWS){
    const int rr = tid;
    float g = gminW[0][rr];
    #pragma unroll
    for (int q=1;q<8;q++) g = fminf(g, gminW[q][rr]);
    const float fthr = g + MARGIN;
    int c = cntS[rr]; if (c > CAP) c = CAP;
    const int grow = blk*BROWS + rr;
    int sel = 0;
    for (int i=0;i<c;i++){
      if (listV[rr][i] <= fthr && sel < CEXP){
        cand[(size_t)grow*CEXP + sel] = (unsigned short)listI[rr][i];
        sel++;
      }
    }
    selw[grow] = (unsigned short)sel;
  }
}

/* decideB: 1 thread per row, whole chip. Round-11 chain bodies verbatim. */
__global__ __launch_bounds__(256,1) void vq_decide_kernel(
    const float* __restrict__ ze, const float* __restrict__ W,
    const float* __restrict__ wsq,
    const unsigned short* __restrict__ cand, const unsigned short* __restrict__ selw,
    int* __restrict__ rowcode, int* __restrict__ cnt, float* __restrict__ out)
{
  const int row = blockIdx.x*256 + threadIdx.x;
  const float* zr = ze + (size_t)row*DD;
  /* exact zsq chain */
  float zs = __fmul_rn(zr[0], zr[0]);
  for (int i=1;i<256;i++) zs = __fadd_rn(zs, __fmul_rn(zr[i], zr[i]));
  const int sel = selw[row];
  float bv = 3.4e38f; int bi = 0x7fffffff;
  for (int i=0;i<sel;i++){
    const int idx = cand[(size_t)row*CEXP + i];
    const float* wr = W + (size_t)idx*DD;
    float ss = 0.f;
    for (int k2=0;k2<256;k2++) ss = __fadd_rn(ss, __fmul_rn(zr[k2], wr[k2]));
    const float v = __fadd_rn(__fsub_rn(zs, __fmul_rn(2.0f, ss)), wsq[idx]);
    minmerge(bv, bi, v, idx);
  }
  rowcode[row] = bi;
  out[O_IDX + row] = (float)bi;
  atomicAdd(&cnt[bi], 1);
}

/* exclusive prefix sum over 1024 counts -> offs (with sentinel), pos */
__global__ __launch_bounds__(1024,1) void vq_prefix_kernel(
    const int* __restrict__ cnt, int* __restrict__ offs, int* __restrict__ pos)
{
  __shared__ int s[1024];
  const int tid = threadIdx.x;
  const int c = cnt[tid];
  s[tid] = c;
  __syncthreads();
  #pragma unroll
  for (int off=1; off<1024; off<<=1){
    int v = s[tid];
    int a = (tid >= off) ? s[tid-off] : 0;
    __syncthreads();
    s[tid] = v + a;
    __syncthreads();
  }
  const int ex = s[tid] - c;
  offs[tid] = ex;
  pos[tid]  = ex;
  if (tid == 1023) offs[1024] = NROWS;
}

/* bucket row ids by code */
__global__ __launch_bounds__(256,1) void vq_scatter_kernel(
    const int* __restrict__ rowcode, int* __restrict__ pos, int* __restrict__ bucket)
{
  const int r = blockIdx.x*256 + threadIdx.x;
  const int k = rowcode[r];
  const int slot = atomicAdd(&pos[k], 1);
  bucket[slot] = r;
}

/* chunksum + fused zq epilogue: each wave sums a 32-entry chunk of the
   code-sorted bucket (st flush at code boundaries), and for every entry
   also writes zq_st (W row is L2-hot) and accumulates dist into a
   per-block partial (NO global atomics for dist). 512 blocks x 4 waves. */
__global__ __launch_bounds__(256,4) void vq_chunksum_kernel(
    const float* __restrict__ ze, const float* __restrict__ W,
    const int* __restrict__ bucket, const int* __restrict__ offs,
    float* __restrict__ st, float* __restrict__ out,
    float* __restrict__ dist_part)
{
  __shared__ int offsS[1025];
  __shared__ float dps[4];
  const int tid = threadIdx.x;
  for (int i=tid; i<1025; i+=256) offsS[i] = offs[i];
  __syncthreads();

  const int wv = tid >> 6, lane = tid & 63;
  const int j0 = (blockIdx.x*4 + wv)*32;

  int r, k;
  {
    const int j = j0 + (lane & 31);
    r = bucket[j];
    int lo = 0, hi = 1024;
    #pragma unroll
    for (int it=0; it<10; ++it){
      int mid = (lo + hi) >> 1;
      if (offsS[mid] <= j) lo = mid; else hi = mid;
    }
    k = lo;
  }

  float4 acc = {0.f,0.f,0.f,0.f};
  float distp = 0.f;
  int kprev = __shfl(k, 0);
  #pragma unroll
  for (int g=0; g<4; ++g){
    float4 v[8]; int rk[8]; int rr[8];
    #pragma unroll
    for (int i=0;i<8;i++){
      rr[i] = __shfl(r, g*8+i);
      rk[i] = __shfl(k, g*8+i);
      v[i] = *(const float4*)&ze[(size_t)rr[i]*DD + lane*4];
    }
    #pragma unroll
    for (int i=0;i<8;i++){
      if (rk[i] != kprev){
        atomicAdd(&st[(size_t)kprev*DD + lane*4 + 0], acc.x);
        atomicAdd(&st[(size_t)kprev*DD + lane*4 + 1], acc.y);
        atomicAdd(&st[(size_t)kprev*DD + lane*4 + 2], acc.z);
        atomicAdd(&st[(size_t)kprev*DD + lane*4 + 3], acc.w);
        acc = (float4){0.f,0.f,0.f,0.f};
        kprev = rk[i];
      }
      acc.x += v[i].x; acc.y += v[i].y; acc.z += v[i].z; acc.w += v[i].w;
      /* fused zq epilogue for this row (reference formula) */
      float4 w4 = *(const float4*)&W[(size_t)rk[i]*DD + lane*4];
      float4 o;
      o.x = v[i].x + (w4.x - v[i].x);
      o.y = v[i].y + (w4.y - v[i].y);
      o.z = v[i].z + (w4.z - v[i].z);
      o.w = v[i].w + (w4.w - v[i].w);
      *(float4*)&out[O_ZQ + (size_t)rr[i]*DD + lane*4] = o;
      float dx;
      dx = w4.x - v[i].x; distp += dx*dx;
      dx = w4.y - v[i].y; distp += dx*dx;
      dx = w4.z - v[i].z; distp += dx*dx;
      dx = w4.w - v[i].w; distp += dx*dx;
    }
  }
  atomicAdd(&st[(size_t)kprev*DD + lane*4 + 0], acc.x);
  atomicAdd(&st[(size_t)kprev*DD + lane*4 + 1], acc.y);
  atomicAdd(&st[(size_t)kprev*DD + lane*4 + 2], acc.z);
  atomicAdd(&st[(size_t)kprev*DD + lane*4 + 3], acc.w);

  /* dist: wave reduce -> block partial (no global atomics) */
  #pragma unroll
  for (int m=1; m<64; m<<=1) distp += __shfl_xor(distp, m);
  if (lane == 0) dps[wv] = distp;
  __syncthreads();
  if (tid == 0) dist_part[blockIdx.x] = dps[0]+dps[1]+dps[2]+dps[3];
}

/* EMA tail: mt_new, embedW_new, Nt_new; block 0 also finalizes dist */
__global__ __launch_bounds__(256,1) void vq_tail_kernel(
    const float* __restrict__ mt, const float* __restrict__ Nt,
    const float* __restrict__ st, const int* __restrict__ cnt,
    const float* __restrict__ dist_part, float* __restrict__ out)
{
  const float G   = 0.99f;
  const float OMG = (float)(1.0 - 0.99);
  const int i = blockIdx.x*256 + threadIdx.x;   /* 0..KD-1 */
  const int k = i >> 8;
  const float ntn = __fadd_rn(__fmul_rn(G, Nt[k]), __fmul_rn(OMG, (float)cnt[k]));
  const float mtn = __fadd_rn(__fmul_rn(G, mt[i]), __fmul_rn(OMG, st[i]));
  out[O_MT  + i] = mtn;
  out[O_EMB + i] = mtn / ntn;
  if ((i & 255) == 0) out[O_NT + k] = ntn;

  if (blockIdx.x == 0){
    __shared__ float ds[4];
    const int tid = threadIdx.x;
    float s = dist_part[tid] + dist_part[tid + 256];
    #pragma unroll
    for (int m=1; m<64; m<<=1) s += __shfl_xor(s, m);
    if ((tid & 63) == 0) ds[tid >> 6] = s;
    __syncthreads();
    if (tid == 0) out[O_DIST] = (ds[0]+ds[1]+ds[2]+ds[3]) * (1.0f/16777216.0f);
  }
}

extern "C" void kernel_launch(void* const* d_in, const int* in_sizes, int n_in,
                              void* d_out, int out_size, void* d_ws, size_t ws_size,
                              hipStream_t stream){
  const float* ze = (const float*)d_in[0];
  const float* W  = (const float*)d_in[1];
  const float* mt = (const float*)d_in[2];
  const float* Nt = (const float*)d_in[3];
  float* out  = (float*)d_out;
  float* ws   = (float*)d_ws;
  float*  wsq  = ws + WS_WSQ;
  bf16x8* wpk  = (bf16x8*)(ws + WS_WPK);
  int*    rowc = (int*)(ws + WS_ROWC);
  int*    buck = (int*)(ws + WS_BUCK);
  int*    offs = (int*)(ws + WS_OFFS);
  int*    pos  = (int*)(ws + WS_POS);
  int*    cnt  = (int*)(ws + WS_CNT);
  float*  st   = ws + WS_ST;
  unsigned short* cand = (unsigned short*)(ws + WS_CAND);
  unsigned short* selw = (unsigned short*)(ws + WS_SEL);
  float*  distp = ws + WS_DISTP;

  /* zero cnt + legacy dist slot + st in one shot (contiguous) */
  hipMemsetAsync((void*)(ws + WS_CNT), 0, (size_t)(KC + 4 + KD)*sizeof(float), stream);
  vq_prep_kernel    <<<KC/4,        256, 0, stream>>>(W, wsq, wpk);
  vq_screen_kernel  <<<NROWS/BROWS, 512, 0, stream>>>(ze, wpk, wsq, cand, selw);
  vq_decide_kernel  <<<NROWS/256,   256, 0, stream>>>(ze, W, wsq, cand, selw, rowc, cnt, out);
  vq_prefix_kernel  <<<1,          1024, 0, stream>>>(cnt, offs, pos);
  vq_scatter_kernel <<<NROWS/256,   256, 0, stream>>>(rowc, pos, buck);
  vq_chunksum_kernel<<<NROWS/128,   256, 0, stream>>>(ze, W, buck, offs, st, out, distp);
  vq_tail_kernel    <<<KD/256,      256, 0, stream>>>(mt, Nt, st, cnt, distp, out);
}

// Round 17
// 284.651 us; speedup vs baseline: 2.5582x; 2.5582x over previous
//
#include <hip/hip_runtime.h>

#define NROWS 65536
#define KC    1024
#define DD    256
#define ND    (NROWS*DD)      /* 16777216 */
#define KD    (KC*DD)         /* 262144 */
#define BROWS 64              /* rows per screen block */
#define CAP   24              /* LDS candidate list capacity per row */
#define CEXP  12              /* exported (filtered) candidates per row */
#define MARGIN 3.0f           /* >=2E for bf16-screen vs exact-replica (~14 sigma) */

/* output offsets (floats), concatenated in reference return order */
#define O_ZQ   0
#define O_DIST ND
#define O_IDX  (ND+1)
#define O_EMB  (ND+1+NROWS)
#define O_MT   (O_EMB+KD)
#define O_NT   (O_MT+KD)

/* ws float offsets */
#define WS_WSQ   0
#define WS_WPK   KC                    /* 131072 floats = 512KB bf16 W frags */
#define WS_ROWC  (KC+131072)           /* NROWS ints */
#define WS_BUCK  (WS_ROWC+NROWS)       /* NROWS ints */
#define WS_OFFS  (WS_BUCK+NROWS)       /* 1028 ints (1025 used) */
#define WS_POS   (WS_OFFS+1028)        /* KC ints */
#define WS_CNT   (WS_POS+KC)           /* KC ints */
#define WS_DIST  (WS_CNT+KC)           /* 1 float + 3 pad (legacy slot) */
#define WS_ST    (WS_DIST+4)           /* KD floats */
#define WS_CAND  (WS_ST+KD)            /* NROWS*CEXP u16 */
#define WS_SEL   (WS_CAND+NROWS*CEXP/2)/* NROWS u16 -> NROWS/2 floats */
#define WS_DISTP (WS_SEL+NROWS/2)      /* 512 floats: per-block dist partials */

typedef __attribute__((ext_vector_type(8))) short bf16x8;
typedef __attribute__((ext_vector_type(4))) float f32x4;

/* ===== exact-replica arithmetic contract (validated rounds 5-16) =====
   ref dist d2[r][c] = fadd( fsub( zsq[r], fmul(2, dot) ), wsq[c] )
   dot  = sequential ascending-k, SEPARATE mul+add roundings, single acc
   zsq/wsq = strict sequential sum of squares (mul+add, ascending)
   argmin  = first occurrence of min.
   Screen = bf16 MFMA (row-constant zsq dropped, absorbed in MARGIN);
   every code within MARGIN of the row's global screen min is rescored
   with the exact chain.  This round vs round 16: ONLY the screen kernel's
   launch bounds change (512,6)->(512,4).  (512,6) forced VGPR 96->40 and
   spilled the MFMA accumulators to scratch (FETCH 95->738MB, WRITE
   68KB->1.37GB, 570us).  (512,4) = 2 blocks/CU, VGPR cap 128, no spill. */

static __device__ __forceinline__ void minmerge(float& bv, int& bi, float ov, int oi){
  if (ov < bv || (ov == bv && oi < bi)) { bv = ov; bi = oi; }
}

static __device__ __forceinline__ unsigned short f2bf(float f){
  unsigned u = __float_as_uint(f);
  unsigned r = (u + 0x7FFFu + ((u>>16)&1u)) >> 16;   /* RNE */
  return (unsigned short)r;
}
static __device__ __forceinline__ bf16x8 cvt8(float4 a, float4 b){
  bf16x8 v;
  v[0]=(short)f2bf(a.x); v[1]=(short)f2bf(a.y); v[2]=(short)f2bf(a.z); v[3]=(short)f2bf(a.w);
  v[4]=(short)f2bf(b.x); v[5]=(short)f2bf(b.y); v[6]=(short)f2bf(b.z); v[7]=(short)f2bf(b.w);
  return v;
}

/* prologue: one wave per code. Lanes 0-31 pack bf16 B-fragments,
   lane 32 runs the exact wsq chain (scalar, round-11 verbatim). */
__global__ __launch_bounds__(256,1) void vq_prep_kernel(const float* __restrict__ W,
                                                        float* __restrict__ wsq,
                                                        bf16x8* __restrict__ wpk){
  const int wv = threadIdx.x>>6, lane = threadIdx.x&63;
  const int k = blockIdx.x*4 + wv;
  const float* wr = W + (size_t)k*DD;
  if (lane < 32){
    float4 x = *(const float4*)(wr + lane*8);
    float4 y = *(const float4*)(wr + lane*8 + 4);
    wpk[((k>>4)*8 + (lane>>2))*64 + (k&15) + 16*(lane&3)] = cvt8(x,y);
  } else if (lane == 32){
    float s = __fmul_rn(wr[0], wr[0]);
    for (int i=1;i<256;i++) s = __fadd_rn(s, __fmul_rn(wr[i], wr[i]));
    wsq[k] = s;
  }
}

/* screenA: 512 thr = 8 waves (2 row-groups x 4 col-groups), 64 rows x 1024
   codes per block, 1024 blocks, 2 blocks/CU (no spill: VGPR cap 128). */
__global__ __launch_bounds__(512,4) void vq_screen_kernel(
    const float* __restrict__ ze, const bf16x8* __restrict__ wpk,
    const float* __restrict__ wsq,
    unsigned short* __restrict__ cand, unsigned short* __restrict__ selw)
{
  __shared__ bf16x8 apkS[2048];        /* 32 KB: A fragments, linear */
  __shared__ float  wsqS[KC];          /* 4 KB */
  __shared__ float  gminW[8][BROWS];   /* 2 KB */
  __shared__ int    cntS[BROWS];
  __shared__ float  listV[BROWS][CAP]; /* 6 KB */
  __shared__ int    listI[BROWS][CAP]; /* 6 KB */

  const int tid = threadIdx.x;
  const int blk = blockIdx.x;
  const float* zb = ze + (size_t)blk*BROWS*DD;

  /* ---- phase 1: convert z tile to A fragments + init ---- */
  #pragma unroll
  for (int it=0; it<4; ++it){
    const int g  = it*512 + tid;
    const int r  = g >> 5;
    const int kb = g & 31;
    float4 a = *(const float4*)&zb[(size_t)r*DD + kb*8];
    float4 b = *(const float4*)&zb[(size_t)r*DD + kb*8 + 4];
    apkS[((r>>4)*8 + (kb>>2))*64 + (r&15) + 16*(kb&3)] = cvt8(a,b);
  }
  wsqS[tid]     = wsq[tid];
  wsqS[tid+512] = wsq[tid+512];
  if (tid < BROWS) cntS[tid] = 0;
  __syncthreads();

  /* ---- phase 2: MFMA screen + per-group min + candidate collection ---- */
  const int lane = tid & 63;
  const int wv   = tid >> 6;
  const int rg   = wv >> 2;
  const int cg   = wv & 3;

  #pragma unroll
  for (int p=0; p<2; ++p){
    f32x4 acc[2][8];
    #pragma unroll
    for (int mt=0; mt<2; ++mt)
      #pragma unroll
      for (int nt=0; nt<8; ++nt)
        acc[mt][nt] = (f32x4){0.f,0.f,0.f,0.f};

    #pragma unroll
    for (int s=0; s<8; ++s){
      bf16x8 af[2], bf[8];
      #pragma unroll
      for (int mt=0; mt<2; ++mt)
        af[mt] = apkS[((rg*2+mt)*8 + s)*64 + lane];
      #pragma unroll
      for (int nt=0; nt<8; ++nt)
        bf[nt] = wpk[(size_t)(((cg*16 + p*8 + nt)*8 + s)*64 + lane)];
      #pragma unroll
      for (int mt=0; mt<2; ++mt)
        #pragma unroll
        for (int nt=0; nt<8; ++nt)
          acc[mt][nt] = __builtin_amdgcn_mfma_f32_16x16x32_bf16(af[mt], bf[nt], acc[mt][nt], 0,0,0);
    }

    /* screen value = wsq - 2*dot (row-constant zsq dropped) */
    #pragma unroll
    for (int mt=0; mt<2; ++mt){
      #pragma unroll
      for (int r=0; r<4; ++r){
        const int row = rg*32 + mt*16 + (lane>>4)*4 + r;
        float dv[8]; float mn = 3.4e38f;
        #pragma unroll
        for (int nt=0; nt<8; ++nt){
          const int col = (cg*16 + p*8 + nt)*16 + (lane&15);
          dv[nt] = __fsub_rn(wsqS[col], __fmul_rn(2.0f, acc[mt][nt][r]));
          mn = fminf(mn, dv[nt]);
        }
        #pragma unroll
        for (int m=1; m<16; m<<=1) mn = fminf(mn, __shfl_xor(mn, m));
        if ((lane & 15) == 0) gminW[p*4+cg][row] = mn;
        const float thr = mn + MARGIN;
        #pragma unroll
        for (int nt=0; nt<8; ++nt){
          if (dv[nt] <= thr){
            int slot = atomicAdd(&cntS[row], 1);
            if (slot < CAP){
              listV[row][slot] = dv[nt];
              listI[row][slot] = (cg*16 + p*8 + nt)*16 + (lane&15);
            }
          }
        }
      }
    }
  }
  __syncthreads();

  /* ---- phase 3': global-min filter + export ---- */
  if (tid < BROWS){
    const int rr = tid;
    float g = gminW[0][rr];
    #pragma unroll
    for (int q=1;q<8;q++) g = fminf(g, gminW[q][rr]);
    const float fthr = g + MARGIN;
    int c = cntS[rr]; if (c > CAP) c = CAP;
    const int grow = blk*BROWS + rr;
    int sel = 0;
    for (int i=0;i<c;i++){
      if (listV[rr][i] <= fthr && sel < CEXP){
        cand[(size_t)grow*CEXP + sel] = (unsigned short)listI[rr][i];
        sel++;
      }
    }
    selw[grow] = (unsigned short)sel;
  }
}

/* decideB: 1 thread per row, whole chip. Round-11 chain bodies verbatim. */
__global__ __launch_bounds__(256,1) void vq_decide_kernel(
    const float* __restrict__ ze, const float* __restrict__ W,
    const float* __restrict__ wsq,
    const unsigned short* __restrict__ cand, const unsigned short* __restrict__ selw,
    int* __restrict__ rowcode, int* __restrict__ cnt, float* __restrict__ out)
{
  const int row = blockIdx.x*256 + threadIdx.x;
  const float* zr = ze + (size_t)row*DD;
  /* exact zsq chain */
  float zs = __fmul_rn(zr[0], zr[0]);
  for (int i=1;i<256;i++) zs = __fadd_rn(zs, __fmul_rn(zr[i], zr[i]));
  const int sel = selw[row];
  float bv = 3.4e38f; int bi = 0x7fffffff;
  for (int i=0;i<sel;i++){
    const int idx = cand[(size_t)row*CEXP + i];
    const float* wr = W + (size_t)idx*DD;
    float ss = 0.f;
    for (int k2=0;k2<256;k2++) ss = __fadd_rn(ss, __fmul_rn(zr[k2], wr[k2]));
    const float v = __fadd_rn(__fsub_rn(zs, __fmul_rn(2.0f, ss)), wsq[idx]);
    minmerge(bv, bi, v, idx);
  }
  rowcode[row] = bi;
  out[O_IDX + row] = (float)bi;
  atomicAdd(&cnt[bi], 1);
}

/* exclusive prefix sum over 1024 counts -> offs (with sentinel), pos */
__global__ __launch_bounds__(1024,1) void vq_prefix_kernel(
    const int* __restrict__ cnt, int* __restrict__ offs, int* __restrict__ pos)
{
  __shared__ int s[1024];
  const int tid = threadIdx.x;
  const int c = cnt[tid];
  s[tid] = c;
  __syncthreads();
  #pragma unroll
  for (int off=1; off<1024; off<<=1){
    int v = s[tid];
    int a = (tid >= off) ? s[tid-off] : 0;
    __syncthreads();
    s[tid] = v + a;
    __syncthreads();
  }
  const int ex = s[tid] - c;
  offs[tid] = ex;
  pos[tid]  = ex;
  if (tid == 1023) offs[1024] = NROWS;
}

/* bucket row ids by code */
__global__ __launch_bounds__(256,1) void vq_scatter_kernel(
    const int* __restrict__ rowcode, int* __restrict__ pos, int* __restrict__ bucket)
{
  const int r = blockIdx.x*256 + threadIdx.x;
  const int k = rowcode[r];
  const int slot = atomicAdd(&pos[k], 1);
  bucket[slot] = r;
}

/* chunksum + fused zq epilogue: each wave sums a 32-entry chunk of the
   code-sorted bucket (st flush at code boundaries), and for every entry
   also writes zq_st (W row is L2-hot) and accumulates dist into a
   per-block partial (NO global atomics for dist). 512 blocks x 4 waves. */
__global__ __launch_bounds__(256,4) void vq_chunksum_kernel(
    const float* __restrict__ ze, const float* __restrict__ W,
    const int* __restrict__ bucket, const int* __restrict__ offs,
    float* __restrict__ st, float* __restrict__ out,
    float* __restrict__ dist_part)
{
  __shared__ int offsS[1025];
  __shared__ float dps[4];
  const int tid = threadIdx.x;
  for (int i=tid; i<1025; i+=256) offsS[i] = offs[i];
  __syncthreads();

  const int wv = tid >> 6, lane = tid & 63;
  const int j0 = (blockIdx.x*4 + wv)*32;

  int r, k;
  {
    const int j = j0 + (lane & 31);
    r = bucket[j];
    int lo = 0, hi = 1024;
    #pragma unroll
    for (int it=0; it<10; ++it){
      int mid = (lo + hi) >> 1;
      if (offsS[mid] <= j) lo = mid; else hi = mid;
    }
    k = lo;
  }

  float4 acc = {0.f,0.f,0.f,0.f};
  float distp = 0.f;
  int kprev = __shfl(k, 0);
  #pragma unroll
  for (int g=0; g<4; ++g){
    float4 v[8]; int rk[8]; int rr[8];
    #pragma unroll
    for (int i=0;i<8;i++){
      rr[i] = __shfl(r, g*8+i);
      rk[i] = __shfl(k, g*8+i);
      v[i] = *(const float4*)&ze[(size_t)rr[i]*DD + lane*4];
    }
    #pragma unroll
    for (int i=0;i<8;i++){
      if (rk[i] != kprev){
        atomicAdd(&st[(size_t)kprev*DD + lane*4 + 0], acc.x);
        atomicAdd(&st[(size_t)kprev*DD + lane*4 + 1], acc.y);
        atomicAdd(&st[(size_t)kprev*DD + lane*4 + 2], acc.z);
        atomicAdd(&st[(size_t)kprev*DD + lane*4 + 3], acc.w);
        acc = (float4){0.f,0.f,0.f,0.f};
        kprev = rk[i];
      }
      acc.x += v[i].x; acc.y += v[i].y; acc.z += v[i].z; acc.w += v[i].w;
      /* fused zq epilogue for this row (reference formula) */
      float4 w4 = *(const float4*)&W[(size_t)rk[i]*DD + lane*4];
      float4 o;
      o.x = v[i].x + (w4.x - v[i].x);
      o.y = v[i].y + (w4.y - v[i].y);
      o.z = v[i].z + (w4.z - v[i].z);
      o.w = v[i].w + (w4.w - v[i].w);
      *(float4*)&out[O_ZQ + (size_t)rr[i]*DD + lane*4] = o;
      float dx;
      dx = w4.x - v[i].x; distp += dx*dx;
      dx = w4.y - v[i].y; distp += dx*dx;
      dx = w4.z - v[i].z; distp += dx*dx;
      dx = w4.w - v[i].w; distp += dx*dx;
    }
  }
  atomicAdd(&st[(size_t)kprev*DD + lane*4 + 0], acc.x);
  atomicAdd(&st[(size_t)kprev*DD + lane*4 + 1], acc.y);
  atomicAdd(&st[(size_t)kprev*DD + lane*4 + 2], acc.z);
  atomicAdd(&st[(size_t)kprev*DD + lane*4 + 3], acc.w);

  /* dist: wave reduce -> block partial (no global atomics) */
  #pragma unroll
  for (int m=1; m<64; m<<=1) distp += __shfl_xor(distp, m);
  if (lane == 0) dps[wv] = distp;
  __syncthreads();
  if (tid == 0) dist_part[blockIdx.x] = dps[0]+dps[1]+dps[2]+dps[3];
}

/* EMA tail: mt_new, embedW_new, Nt_new; block 0 also finalizes dist */
__global__ __launch_bounds__(256,1) void vq_tail_kernel(
    const float* __restrict__ mt, const float* __restrict__ Nt,
    const float* __restrict__ st, const int* __restrict__ cnt,
    const float* __restrict__ dist_part, float* __restrict__ out)
{
  const float G   = 0.99f;
  const float OMG = (float)(1.0 - 0.99);
  const int i = blockIdx.x*256 + threadIdx.x;   /* 0..KD-1 */
  const int k = i >> 8;
  const float ntn = __fadd_rn(__fmul_rn(G, Nt[k]), __fmul_rn(OMG, (float)cnt[k]));
  const float mtn = __fadd_rn(__fmul_rn(G, mt[i]), __fmul_rn(OMG, st[i]));
  out[O_MT  + i] = mtn;
  out[O_EMB + i] = mtn / ntn;
  if ((i & 255) == 0) out[O_NT + k] = ntn;

  if (blockIdx.x == 0){
    __shared__ float ds[4];
    const int tid = threadIdx.x;
    float s = dist_part[tid] + dist_part[tid + 256];
    #pragma unroll
    for (int m=1; m<64; m<<=1) s += __shfl_xor(s, m);
    if ((tid & 63) == 0) ds[tid >> 6] = s;
    __syncthreads();
    if (tid == 0) out[O_DIST] = (ds[0]+ds[1]+ds[2]+ds[3]) * (1.0f/16777216.0f);
  }
}

extern "C" void kernel_launch(void* const* d_in, const int* in_sizes, int n_in,
                              void* d_out, int out_size, void* d_ws, size_t ws_size,
                              hipStream_t stream){
  const float* ze = (const float*)d_in[0];
  const float* W  = (const float*)d_in[1];
  const float* mt = (const float*)d_in[2];
  const float* Nt = (const float*)d_in[3];
  float* out  = (float*)d_out;
  float* ws   = (float*)d_ws;
  float*  wsq  = ws + WS_WSQ;
  bf16x8* wpk  = (bf16x8*)(ws + WS_WPK);
  int*    rowc = (int*)(ws + WS_ROWC);
  int*    buck = (int*)(ws + WS_BUCK);
  int*    offs = (int*)(ws + WS_OFFS);
  int*    pos  = (int*)(ws + WS_POS);
  int*    cnt  = (int*)(ws + WS_CNT);
  float*  st   = ws + WS_ST;
  unsigned short* cand = (unsigned short*)(ws + WS_CAND);
  unsigned short* selw = (unsigned short*)(ws + WS_SEL);
  float*  distp = ws + WS_DISTP;

  /* zero cnt + legacy dist slot + st in one shot (contiguous) */
  hipMemsetAsync((void*)(ws + WS_CNT), 0, (size_t)(KC + 4 + KD)*sizeof(float), stream);
  vq_prep_kernel    <<<KC/4,        256, 0, stream>>>(W, wsq, wpk);
  vq_screen_kernel  <<<NROWS/BROWS, 512, 0, stream>>>(ze, wpk, wsq, cand, selw);
  vq_decide_kernel  <<<NROWS/256,   256, 0, stream>>>(ze, W, wsq, cand, selw, rowc, cnt, out);
  vq_prefix_kernel  <<<1,          1024, 0, stream>>>(cnt, offs, pos);
  vq_scatter_kernel <<<NROWS/256,   256, 0, stream>>>(rowc, pos, buck);
  vq_chunksum_kernel<<<NROWS/128,   256, 0, stream>>>(ze, W, buck, offs, st, out, distp);
  vq_tail_kernel    <<<KD/256,      256, 0, stream>>>(mt, Nt, st, cnt, distp, out);
}

// Round 18
// 253.295 us; speedup vs baseline: 2.8749x; 1.1238x over previous
//
#include <hip/hip_runtime.h>

#define NROWS 65536
#define KC    1024
#define DD    256
#define ND    (NROWS*DD)      /* 16777216 */
#define KD    (KC*DD)         /* 262144 */
#define BROWS 64              /* rows per screen block */
#define CAP   32              /* LDS candidate list capacity per row */
#define CEXP  12              /* exported (filtered) candidates per row */
#define MARGIN 3.0f           /* >=2E for bf16-screen vs exact-replica (~14 sigma) */

/* output offsets (floats), concatenated in reference return order */
#define O_ZQ   0
#define O_DIST ND
#define O_IDX  (ND+1)
#define O_EMB  (ND+1+NROWS)
#define O_MT   (O_EMB+KD)
#define O_NT   (O_MT+KD)

/* ws float offsets */
#define WS_WSQ   0
#define WS_WPK   KC                    /* 131072 floats = 512KB bf16 W frags */
#define WS_ROWC  (KC+131072)           /* NROWS ints */
#define WS_BUCK  (WS_ROWC+NROWS)       /* NROWS ints */
#define WS_OFFS  (WS_BUCK+NROWS)       /* 1028 ints (1025 used) */
#define WS_POS   (WS_OFFS+1028)        /* KC ints */
#define WS_CNT   (WS_POS+KC)           /* KC ints */
#define WS_DIST  (WS_CNT+KC)           /* 1 float + 3 pad (legacy slot) */
#define WS_ST    (WS_DIST+4)           /* KD floats */
#define WS_CAND  (WS_ST+KD)            /* NROWS*CEXP u16 */
#define WS_SEL   (WS_CAND+NROWS*CEXP/2)/* NROWS u16 -> NROWS/2 floats */
#define WS_DISTP (WS_SEL+NROWS/2)      /* 512 floats: per-block dist partials */

typedef __attribute__((ext_vector_type(8))) short bf16x8;
typedef __attribute__((ext_vector_type(4))) float f32x4;

/* ===== exact-replica arithmetic contract (validated rounds 5-17) =====
   ref dist d2[r][c] = fadd( fsub( zsq[r], fmul(2, dot) ), wsq[c] )
   dot  = sequential ascending-k, SEPARATE mul+add roundings, single acc
   zsq/wsq = strict sequential sum of squares (mul+add, ascending)
   argmin  = first occurrence of min.
   Screen = bf16 MFMA (row-constant zsq dropped, absorbed in MARGIN);
   every code within MARGIN of the row's global screen min is rescored
   with the exact chain (per-group collection with thr = group_min+MARGIN
   is a superset, proof independent of group count).
   This round vs r17: screen register tiling only — col pass 2x128 ->
   4x64 so acc[2][4]+bf[4]+af[2] ~= 56-68 VGPR fits the arg2=4 cap of 64
   WITHOUT spill (r17: needed 96, cap 64 -> 50MB scratch traffic).
   16 groups -> gminW[16], CAP 24->32. Decide/chunksum/etc byte-identical. */

static __device__ __forceinline__ void minmerge(float& bv, int& bi, float ov, int oi){
  if (ov < bv || (ov == bv && oi < bi)) { bv = ov; bi = oi; }
}

static __device__ __forceinline__ unsigned short f2bf(float f){
  unsigned u = __float_as_uint(f);
  unsigned r = (u + 0x7FFFu + ((u>>16)&1u)) >> 16;   /* RNE */
  return (unsigned short)r;
}
static __device__ __forceinline__ bf16x8 cvt8(float4 a, float4 b){
  bf16x8 v;
  v[0]=(short)f2bf(a.x); v[1]=(short)f2bf(a.y); v[2]=(short)f2bf(a.z); v[3]=(short)f2bf(a.w);
  v[4]=(short)f2bf(b.x); v[5]=(short)f2bf(b.y); v[6]=(short)f2bf(b.z); v[7]=(short)f2bf(b.w);
  return v;
}

/* prologue: one wave per code. Lanes 0-31 pack bf16 B-fragments,
   lane 32 runs the exact wsq chain (scalar, round-11 verbatim). */
__global__ __launch_bounds__(256,1) void vq_prep_kernel(const float* __restrict__ W,
                                                        float* __restrict__ wsq,
                                                        bf16x8* __restrict__ wpk){
  const int wv = threadIdx.x>>6, lane = threadIdx.x&63;
  const int k = blockIdx.x*4 + wv;
  const float* wr = W + (size_t)k*DD;
  if (lane < 32){
    float4 x = *(const float4*)(wr + lane*8);
    float4 y = *(const float4*)(wr + lane*8 + 4);
    wpk[((k>>4)*8 + (lane>>2))*64 + (k&15) + 16*(lane&3)] = cvt8(x,y);
  } else if (lane == 32){
    float s = __fmul_rn(wr[0], wr[0]);
    for (int i=1;i<256;i++) s = __fadd_rn(s, __fmul_rn(wr[i], wr[i]));
    wsq[k] = s;
  }
}

/* screenA: 512 thr = 8 waves (2 row-groups x 4 col-groups), 64 rows x 1024
   codes per block, 1024 blocks. 4 col passes of 64 -> acc[2][4], VGPR~60,
   no spill at the arg2=4 cap (64). */
__global__ __launch_bounds__(512,4) void vq_screen_kernel(
    const float* __restrict__ ze, const bf16x8* __restrict__ wpk,
    const float* __restrict__ wsq,
    unsigned short* __restrict__ cand, unsigned short* __restrict__ selw)
{
  __shared__ bf16x8 apkS[2048];        /* 32 KB: A fragments, linear */
  __shared__ float  wsqS[KC];          /* 4 KB */
  __shared__ float  gminW[16][BROWS];  /* 4 KB: per-(pass,cg) row mins */
  __shared__ int    cntS[BROWS];
  __shared__ float  listV[BROWS][CAP]; /* 8 KB */
  __shared__ int    listI[BROWS][CAP]; /* 8 KB */

  const int tid = threadIdx.x;
  const int blk = blockIdx.x;
  const float* zb = ze + (size_t)blk*BROWS*DD;

  /* ---- phase 1: convert z tile to A fragments + init ---- */
  #pragma unroll
  for (int it=0; it<4; ++it){
    const int g  = it*512 + tid;
    const int r  = g >> 5;
    const int kb = g & 31;
    float4 a = *(const float4*)&zb[(size_t)r*DD + kb*8];
    float4 b = *(const float4*)&zb[(size_t)r*DD + kb*8 + 4];
    apkS[((r>>4)*8 + (kb>>2))*64 + (r&15) + 16*(kb&3)] = cvt8(a,b);
  }
  wsqS[tid]     = wsq[tid];
  wsqS[tid+512] = wsq[tid+512];
  if (tid < BROWS) cntS[tid] = 0;
  __syncthreads();

  /* ---- phase 2: MFMA screen + per-group min + candidate collection ---- */
  const int lane = tid & 63;
  const int wv   = tid >> 6;
  const int rg   = wv >> 2;
  const int cg   = wv & 3;

  for (int p=0; p<4; ++p){
    f32x4 acc[2][4];
    #pragma unroll
    for (int mt=0; mt<2; ++mt)
      #pragma unroll
      for (int nt=0; nt<4; ++nt)
        acc[mt][nt] = (f32x4){0.f,0.f,0.f,0.f};

    #pragma unroll
    for (int s=0; s<8; ++s){
      bf16x8 af[2], bf[4];
      #pragma unroll
      for (int mt=0; mt<2; ++mt)
        af[mt] = apkS[((rg*2+mt)*8 + s)*64 + lane];
      #pragma unroll
      for (int nt=0; nt<4; ++nt)
        bf[nt] = wpk[(size_t)(((cg*16 + p*4 + nt)*8 + s)*64 + lane)];
      #pragma unroll
      for (int mt=0; mt<2; ++mt)
        #pragma unroll
        for (int nt=0; nt<4; ++nt)
          acc[mt][nt] = __builtin_amdgcn_mfma_f32_16x16x32_bf16(af[mt], bf[nt], acc[mt][nt], 0,0,0);
    }

    /* screen value = wsq - 2*dot (row-constant zsq dropped) */
    #pragma unroll
    for (int mt=0; mt<2; ++mt){
      #pragma unroll
      for (int r=0; r<4; ++r){
        const int row = rg*32 + mt*16 + (lane>>4)*4 + r;
        float dv[4]; float mn = 3.4e38f;
        #pragma unroll
        for (int nt=0; nt<4; ++nt){
          const int col = (cg*16 + p*4 + nt)*16 + (lane&15);
          dv[nt] = __fsub_rn(wsqS[col], __fmul_rn(2.0f, acc[mt][nt][r]));
          mn = fminf(mn, dv[nt]);
        }
        #pragma unroll
        for (int m=1; m<16; m<<=1) mn = fminf(mn, __shfl_xor(mn, m));
        if ((lane & 15) == 0) gminW[p*4+cg][row] = mn;
        const float thr = mn + MARGIN;
        #pragma unroll
        for (int nt=0; nt<4; ++nt){
          if (dv[nt] <= thr){
            int slot = atomicAdd(&cntS[row], 1);
            if (slot < CAP){
              listV[row][slot] = dv[nt];
              listI[row][slot] = (cg*16 + p*4 + nt)*16 + (lane&15);
            }
          }
        }
      }
    }
  }
  __syncthreads();

  /* ---- phase 3': global-min filter + export ---- */
  if (tid < BROWS){
    const int rr = tid;
    float g = gminW[0][rr];
    #pragma unroll
    for (int q=1;q<16;q++) g = fminf(g, gminW[q][rr]);
    const float fthr = g + MARGIN;
    int c = cntS[rr]; if (c > CAP) c = CAP;
    const int grow = blk*BROWS + rr;
    int sel = 0;
    for (int i=0;i<c;i++){
      if (listV[rr][i] <= fthr && sel < CEXP){
        cand[(size_t)grow*CEXP + sel] = (unsigned short)listI[rr][i];
        sel++;
      }
    }
    selw[grow] = (unsigned short)sel;
  }
}

/* decideB: 1 thread per row, whole chip. Round-11 chain bodies verbatim. */
__global__ __launch_bounds__(256,1) void vq_decide_kernel(
    const float* __restrict__ ze, const float* __restrict__ W,
    const float* __restrict__ wsq,
    const unsigned short* __restrict__ cand, const unsigned short* __restrict__ selw,
    int* __restrict__ rowcode, int* __restrict__ cnt, float* __restrict__ out)
{
  const int row = blockIdx.x*256 + threadIdx.x;
  const float* zr = ze + (size_t)row*DD;
  /* exact zsq chain */
  float zs = __fmul_rn(zr[0], zr[0]);
  for (int i=1;i<256;i++) zs = __fadd_rn(zs, __fmul_rn(zr[i], zr[i]));
  const int sel = selw[row];
  float bv = 3.4e38f; int bi = 0x7fffffff;
  for (int i=0;i<sel;i++){
    const int idx = cand[(size_t)row*CEXP + i];
    const float* wr = W + (size_t)idx*DD;
    float ss = 0.f;
    for (int k2=0;k2<256;k2++) ss = __fadd_rn(ss, __fmul_rn(zr[k2], wr[k2]));
    const float v = __fadd_rn(__fsub_rn(zs, __fmul_rn(2.0f, ss)), wsq[idx]);
    minmerge(bv, bi, v, idx);
  }
  rowcode[row] = bi;
  out[O_IDX + row] = (float)bi;
  atomicAdd(&cnt[bi], 1);
}

/* exclusive prefix sum over 1024 counts -> offs (with sentinel), pos */
__global__ __launch_bounds__(1024,1) void vq_prefix_kernel(
    const int* __restrict__ cnt, int* __restrict__ offs, int* __restrict__ pos)
{
  __shared__ int s[1024];
  const int tid = threadIdx.x;
  const int c = cnt[tid];
  s[tid] = c;
  __syncthreads();
  #pragma unroll
  for (int off=1; off<1024; off<<=1){
    int v = s[tid];
    int a = (tid >= off) ? s[tid-off] : 0;
    __syncthreads();
    s[tid] = v + a;
    __syncthreads();
  }
  const int ex = s[tid] - c;
  offs[tid] = ex;
  pos[tid]  = ex;
  if (tid == 1023) offs[1024] = NROWS;
}

/* bucket row ids by code */
__global__ __launch_bounds__(256,1) void vq_scatter_kernel(
    const int* __restrict__ rowcode, int* __restrict__ pos, int* __restrict__ bucket)
{
  const int r = blockIdx.x*256 + threadIdx.x;
  const int k = rowcode[r];
  const int slot = atomicAdd(&pos[k], 1);
  bucket[slot] = r;
}

/* chunksum + fused zq epilogue: each wave sums a 32-entry chunk of the
   code-sorted bucket (st flush at code boundaries), and for every entry
   also writes zq_st and accumulates dist into per-block partials. */
__global__ __launch_bounds__(256,4) void vq_chunksum_kernel(
    const float* __restrict__ ze, const float* __restrict__ W,
    const int* __restrict__ bucket, const int* __restrict__ offs,
    float* __restrict__ st, float* __restrict__ out,
    float* __restrict__ dist_part)
{
  __shared__ int offsS[1025];
  __shared__ float dps[4];
  const int tid = threadIdx.x;
  for (int i=tid; i<1025; i+=256) offsS[i] = offs[i];
  __syncthreads();

  const int wv = tid >> 6, lane = tid & 63;
  const int j0 = (blockIdx.x*4 + wv)*32;

  int r, k;
  {
    const int j = j0 + (lane & 31);
    r = bucket[j];
    int lo = 0, hi = 1024;
    #pragma unroll
    for (int it=0; it<10; ++it){
      int mid = (lo + hi) >> 1;
      if (offsS[mid] <= j) lo = mid; else hi = mid;
    }
    k = lo;
  }

  float4 acc = {0.f,0.f,0.f,0.f};
  float distp = 0.f;
  int kprev = __shfl(k, 0);
  #pragma unroll
  for (int g=0; g<4; ++g){
    float4 v[8]; int rk[8]; int rr[8];
    #pragma unroll
    for (int i=0;i<8;i++){
      rr[i] = __shfl(r, g*8+i);
      rk[i] = __shfl(k, g*8+i);
      v[i] = *(const float4*)&ze[(size_t)rr[i]*DD + lane*4];
    }
    #pragma unroll
    for (int i=0;i<8;i++){
      if (rk[i] != kprev){
        atomicAdd(&st[(size_t)kprev*DD + lane*4 + 0], acc.x);
        atomicAdd(&st[(size_t)kprev*DD + lane*4 + 1], acc.y);
        atomicAdd(&st[(size_t)kprev*DD + lane*4 + 2], acc.z);
        atomicAdd(&st[(size_t)kprev*DD + lane*4 + 3], acc.w);
        acc = (float4){0.f,0.f,0.f,0.f};
        kprev = rk[i];
      }
      acc.x += v[i].x; acc.y += v[i].y; acc.z += v[i].z; acc.w += v[i].w;
      /* fused zq epilogue for this row (reference formula) */
      float4 w4 = *(const float4*)&W[(size_t)rk[i]*DD + lane*4];
      float4 o;
      o.x = v[i].x + (w4.x - v[i].x);
      o.y = v[i].y + (w4.y - v[i].y);
      o.z = v[i].z + (w4.z - v[i].z);
      o.w = v[i].w + (w4.w - v[i].w);
      *(float4*)&out[O_ZQ + (size_t)rr[i]*DD + lane*4] = o;
      float dx;
      dx = w4.x - v[i].x; distp += dx*dx;
      dx = w4.y - v[i].y; distp += dx*dx;
      dx = w4.z - v[i].z; distp += dx*dx;
      dx = w4.w - v[i].w; distp += dx*dx;
    }
  }
  atomicAdd(&st[(size_t)kprev*DD + lane*4 + 0], acc.x);
  atomicAdd(&st[(size_t)kprev*DD + lane*4 + 1], acc.y);
  atomicAdd(&st[(size_t)kprev*DD + lane*4 + 2], acc.z);
  atomicAdd(&st[(size_t)kprev*DD + lane*4 + 3], acc.w);

  /* dist: wave reduce -> block partial (no global atomics) */
  #pragma unroll
  for (int m=1; m<64; m<<=1) distp += __shfl_xor(distp, m);
  if (lane == 0) dps[wv] = distp;
  __syncthreads();
  if (tid == 0) dist_part[blockIdx.x] = dps[0]+dps[1]+dps[2]+dps[3];
}

/* EMA tail: mt_new, embedW_new, Nt_new; block 0 also finalizes dist */
__global__ __launch_bounds__(256,1) void vq_tail_kernel(
    const float* __restrict__ mt, const float* __restrict__ Nt,
    const float* __restrict__ st, const int* __restrict__ cnt,
    const float* __restrict__ dist_part, float* __restrict__ out)
{
  const float G   = 0.99f;
  const float OMG = (float)(1.0 - 0.99);
  const int i = blockIdx.x*256 + threadIdx.x;   /* 0..KD-1 */
  const int k = i >> 8;
  const float ntn = __fadd_rn(__fmul_rn(G, Nt[k]), __fmul_rn(OMG, (float)cnt[k]));
  const float mtn = __fadd_rn(__fmul_rn(G, mt[i]), __fmul_rn(OMG, st[i]));
  out[O_MT  + i] = mtn;
  out[O_EMB + i] = mtn / ntn;
  if ((i & 255) == 0) out[O_NT + k] = ntn;

  if (blockIdx.x == 0){
    __shared__ float ds[4];
    const int tid = threadIdx.x;
    float s = dist_part[tid] + dist_part[tid + 256];
    #pragma unroll
    for (int m=1; m<64; m<<=1) s += __shfl_xor(s, m);
    if ((tid & 63) == 0) ds[tid >> 6] = s;
    __syncthreads();
    if (tid == 0) out[O_DIST] = (ds[0]+ds[1]+ds[2]+ds[3]) * (1.0f/16777216.0f);
  }
}

extern "C" void kernel_launch(void* const* d_in, const int* in_sizes, int n_in,
                              void* d_out, int out_size, void* d_ws, size_t ws_size,
                              hipStream_t stream){
  const float* ze = (const float*)d_in[0];
  const float* W  = (const float*)d_in[1];
  const float* mt = (const float*)d_in[2];
  const float* Nt = (const float*)d_in[3];
  float* out  = (float*)d_out;
  float* ws   = (float*)d_ws;
  float*  wsq  = ws + WS_WSQ;
  bf16x8* wpk  = (bf16x8*)(ws + WS_WPK);
  int*    rowc = (int*)(ws + WS_ROWC);
  int*    buck = (int*)(ws + WS_BUCK);
  int*    offs = (int*)(ws + WS_OFFS);
  int*    pos  = (int*)(ws + WS_POS);
  int*    cnt  = (int*)(ws + WS_CNT);
  float*  st   = ws + WS_ST;
  unsigned short* cand = (unsigned short*)(ws + WS_CAND);
  unsigned short* selw = (unsigned short*)(ws + WS_SEL);
  float*  distp = ws + WS_DISTP;

  /* zero cnt + legacy dist slot + st in one shot (contiguous) */
  hipMemsetAsync((void*)(ws + WS_CNT), 0, (size_t)(KC + 4 + KD)*sizeof(float), stream);
  vq_prep_kernel    <<<KC/4,        256, 0, stream>>>(W, wsq, wpk);
  vq_screen_kernel  <<<NROWS/BROWS, 512, 0, stream>>>(ze, wpk, wsq, cand, selw);
  vq_decide_kernel  <<<NROWS/256,   256, 0, stream>>>(ze, W, wsq, cand, selw, rowc, cnt, out);
  vq_prefix_kernel  <<<1,          1024, 0, stream>>>(cnt, offs, pos);
  vq_scatter_kernel <<<NROWS/256,   256, 0, stream>>>(rowc, pos, buck);
  vq_chunksum_kernel<<<NROWS/128,   256, 0, stream>>>(ze, W, buck, offs, st, out, distp);
  vq_tail_kernel    <<<KD/256,      256, 0, stream>>>(mt, Nt, st, cnt, distp, out);
}

// Round 19
// 252.447 us; speedup vs baseline: 2.8846x; 1.0034x over previous
//
#include <hip/hip_runtime.h>

#define NROWS 65536
#define KC    1024
#define DD    256
#define ND    (NROWS*DD)      /* 16777216 */
#define KD    (KC*DD)         /* 262144 */
#define BROWS 64              /* rows per screen block */
#define CAP   32              /* LDS candidate list capacity per row */
#define CEXP  12              /* exported (filtered) candidates per row */
#define MARGIN 3.0f           /* >=2E for bf16-screen vs exact-replica (~14 sigma) */

/* output offsets (floats), concatenated in reference return order */
#define O_ZQ   0
#define O_DIST ND
#define O_IDX  (ND+1)
#define O_EMB  (ND+1+NROWS)
#define O_MT   (O_EMB+KD)
#define O_NT   (O_MT+KD)

/* ws float offsets */
#define WS_WSQ   0
#define WS_WPK   KC                    /* 131072 floats = 512KB bf16 W frags */
#define WS_ROWC  (KC+131072)           /* NROWS ints */
#define WS_BUCK  (WS_ROWC+NROWS)       /* NROWS ints */
#define WS_OFFS  (WS_BUCK+NROWS)       /* 1028 ints (1025 used) */
#define WS_POS   (WS_OFFS+1028)        /* KC ints */
#define WS_CNT   (WS_POS+KC)           /* KC ints */
#define WS_DIST  (WS_CNT+KC)           /* 1 float + 3 pad (legacy slot) */
#define WS_ST    (WS_DIST+4)           /* KD floats */
#define WS_CAND  (WS_ST+KD)            /* NROWS*CEXP u16 */
#define WS_SEL   (WS_CAND+NROWS*CEXP/2)/* NROWS u16 -> NROWS/2 floats */
#define WS_DISTP (WS_SEL+NROWS/2)      /* 512+ floats: per-block dist partials */

typedef __attribute__((ext_vector_type(8))) short bf16x8;
typedef __attribute__((ext_vector_type(4))) float f32x4;

/* ===== exact-replica arithmetic contract (validated rounds 5-18) =====
   ref dist d2[r][c] = fadd( fsub( zsq[r], fmul(2, dot) ), wsq[c] )
   dot  = sequential ascending-k, SEPARATE mul+add roundings, single acc
   zsq/wsq = strict sequential sum of squares (mul+add, ascending)
   argmin  = first occurrence of min.
   Screen = bf16 MFMA (row-constant zsq dropped, absorbed in MARGIN);
   every code within MARGIN of the row's global screen min is rescored
   with the exact chain.
   This round vs r18 (screen byte-identical):
   - decide: zsq chain interleaved with cand0 dot chain (independent accs,
     each chain's op sequence byte-identical) + float4 loads with in-order
     component use (same values, same op order; 4x fewer load instrs).
   - chunksum: chunk 32->16, grid 512->1024 blocks (16 waves/CU TLP). */

static __device__ __forceinline__ void minmerge(float& bv, int& bi, float ov, int oi){
  if (ov < bv || (ov == bv && oi < bi)) { bv = ov; bi = oi; }
}

static __device__ __forceinline__ unsigned short f2bf(float f){
  unsigned u = __float_as_uint(f);
  unsigned r = (u + 0x7FFFu + ((u>>16)&1u)) >> 16;   /* RNE */
  return (unsigned short)r;
}
static __device__ __forceinline__ bf16x8 cvt8(float4 a, float4 b){
  bf16x8 v;
  v[0]=(short)f2bf(a.x); v[1]=(short)f2bf(a.y); v[2]=(short)f2bf(a.z); v[3]=(short)f2bf(a.w);
  v[4]=(short)f2bf(b.x); v[5]=(short)f2bf(b.y); v[6]=(short)f2bf(b.z); v[7]=(short)f2bf(b.w);
  return v;
}

/* prologue: one wave per code. Lanes 0-31 pack bf16 B-fragments,
   lane 32 runs the exact wsq chain (scalar, round-11 verbatim). */
__global__ __launch_bounds__(256,1) void vq_prep_kernel(const float* __restrict__ W,
                                                        float* __restrict__ wsq,
                                                        bf16x8* __restrict__ wpk){
  const int wv = threadIdx.x>>6, lane = threadIdx.x&63;
  const int k = blockIdx.x*4 + wv;
  const float* wr = W + (size_t)k*DD;
  if (lane < 32){
    float4 x = *(const float4*)(wr + lane*8);
    float4 y = *(const float4*)(wr + lane*8 + 4);
    wpk[((k>>4)*8 + (lane>>2))*64 + (k&15) + 16*(lane&3)] = cvt8(x,y);
  } else if (lane == 32){
    float s = __fmul_rn(wr[0], wr[0]);
    for (int i=1;i<256;i++) s = __fadd_rn(s, __fmul_rn(wr[i], wr[i]));
    wsq[k] = s;
  }
}

/* screenA: r18 verbatim. 512 thr = 8 waves, 64 rows x 1024 codes per block,
   4 col passes of 64 -> acc[2][4], no spill at the arg2=4 cap (64). */
__global__ __launch_bounds__(512,4) void vq_screen_kernel(
    const float* __restrict__ ze, const bf16x8* __restrict__ wpk,
    const float* __restrict__ wsq,
    unsigned short* __restrict__ cand, unsigned short* __restrict__ selw)
{
  __shared__ bf16x8 apkS[2048];        /* 32 KB: A fragments, linear */
  __shared__ float  wsqS[KC];          /* 4 KB */
  __shared__ float  gminW[16][BROWS];  /* 4 KB: per-(pass,cg) row mins */
  __shared__ int    cntS[BROWS];
  __shared__ float  listV[BROWS][CAP]; /* 8 KB */
  __shared__ int    listI[BROWS][CAP]; /* 8 KB */

  const int tid = threadIdx.x;
  const int blk = blockIdx.x;
  const float* zb = ze + (size_t)blk*BROWS*DD;

  /* ---- phase 1: convert z tile to A fragments + init ---- */
  #pragma unroll
  for (int it=0; it<4; ++it){
    const int g  = it*512 + tid;
    const int r  = g >> 5;
    const int kb = g & 31;
    float4 a = *(const float4*)&zb[(size_t)r*DD + kb*8];
    float4 b = *(const float4*)&zb[(size_t)r*DD + kb*8 + 4];
    apkS[((r>>4)*8 + (kb>>2))*64 + (r&15) + 16*(kb&3)] = cvt8(a,b);
  }
  wsqS[tid]     = wsq[tid];
  wsqS[tid+512] = wsq[tid+512];
  if (tid < BROWS) cntS[tid] = 0;
  __syncthreads();

  /* ---- phase 2: MFMA screen + per-group min + candidate collection ---- */
  const int lane = tid & 63;
  const int wv   = tid >> 6;
  const int rg   = wv >> 2;
  const int cg   = wv & 3;

  for (int p=0; p<4; ++p){
    f32x4 acc[2][4];
    #pragma unroll
    for (int mt=0; mt<2; ++mt)
      #pragma unroll
      for (int nt=0; nt<4; ++nt)
        acc[mt][nt] = (f32x4){0.f,0.f,0.f,0.f};

    #pragma unroll
    for (int s=0; s<8; ++s){
      bf16x8 af[2], bf[4];
      #pragma unroll
      for (int mt=0; mt<2; ++mt)
        af[mt] = apkS[((rg*2+mt)*8 + s)*64 + lane];
      #pragma unroll
      for (int nt=0; nt<4; ++nt)
        bf[nt] = wpk[(size_t)(((cg*16 + p*4 + nt)*8 + s)*64 + lane)];
      #pragma unroll
      for (int mt=0; mt<2; ++mt)
        #pragma unroll
        for (int nt=0; nt<4; ++nt)
          acc[mt][nt] = __builtin_amdgcn_mfma_f32_16x16x32_bf16(af[mt], bf[nt], acc[mt][nt], 0,0,0);
    }

    /* screen value = wsq - 2*dot (row-constant zsq dropped) */
    #pragma unroll
    for (int mt=0; mt<2; ++mt){
      #pragma unroll
      for (int r=0; r<4; ++r){
        const int row = rg*32 + mt*16 + (lane>>4)*4 + r;
        float dv[4]; float mn = 3.4e38f;
        #pragma unroll
        for (int nt=0; nt<4; ++nt){
          const int col = (cg*16 + p*4 + nt)*16 + (lane&15);
          dv[nt] = __fsub_rn(wsqS[col], __fmul_rn(2.0f, acc[mt][nt][r]));
          mn = fminf(mn, dv[nt]);
        }
        #pragma unroll
        for (int m=1; m<16; m<<=1) mn = fminf(mn, __shfl_xor(mn, m));
        if ((lane & 15) == 0) gminW[p*4+cg][row] = mn;
        const float thr = mn + MARGIN;
        #pragma unroll
        for (int nt=0; nt<4; ++nt){
          if (dv[nt] <= thr){
            int slot = atomicAdd(&cntS[row], 1);
            if (slot < CAP){
              listV[row][slot] = dv[nt];
              listI[row][slot] = (cg*16 + p*4 + nt)*16 + (lane&15);
            }
          }
        }
      }
    }
  }
  __syncthreads();

  /* ---- phase 3': global-min filter + export ---- */
  if (tid < BROWS){
    const int rr = tid;
    float g = gminW[0][rr];
    #pragma unroll
    for (int q=1;q<16;q++) g = fminf(g, gminW[q][rr]);
    const float fthr = g + MARGIN;
    int c = cntS[rr]; if (c > CAP) c = CAP;
    const int grow = blk*BROWS + rr;
    int sel = 0;
    for (int i=0;i<c;i++){
      if (listV[rr][i] <= fthr && sel < CEXP){
        cand[(size_t)grow*CEXP + sel] = (unsigned short)listI[rr][i];
        sel++;
      }
    }
    selw[grow] = (unsigned short)sel;
  }
}

/* decideB: 1 thread/row. Chains value-identical to r11 (same op sequence);
   zsq interleaved with cand0's dot (independent accumulators, 2x ILP),
   float4 loads with strictly in-order component use (4x fewer load instrs). */
__global__ __launch_bounds__(256,1) void vq_decide_kernel(
    const float* __restrict__ ze, const float* __restrict__ W,
    const float* __restrict__ wsq,
    const unsigned short* __restrict__ cand, const unsigned short* __restrict__ selw,
    int* __restrict__ rowcode, int* __restrict__ cnt, float* __restrict__ out)
{
  const int row = blockIdx.x*256 + threadIdx.x;
  const float4* z4p = (const float4*)(ze + (size_t)row*DD);
  const int sel = selw[row];
  float bv = 3.4e38f; int bi = 0x7fffffff;

  if (sel > 0){
    /* chain A: zsq (seed fmul(z0,z0), ascending) ; chain B: dot cand0
       (seed fadd(0, fmul), ascending) — both exactly r11's sequences */
    const int idx0 = cand[(size_t)row*CEXP];
    const float4* w4p = (const float4*)(W + (size_t)idx0*DD);
    float4 z = z4p[0], w = w4p[0];
    float zs = __fmul_rn(z.x, z.x);
    float ss = __fadd_rn(0.f, __fmul_rn(z.x, w.x));
    zs = __fadd_rn(zs, __fmul_rn(z.y, z.y)); ss = __fadd_rn(ss, __fmul_rn(z.y, w.y));
    zs = __fadd_rn(zs, __fmul_rn(z.z, z.z)); ss = __fadd_rn(ss, __fmul_rn(z.z, w.z));
    zs = __fadd_rn(zs, __fmul_rn(z.w, z.w)); ss = __fadd_rn(ss, __fmul_rn(z.w, w.w));
    for (int k4=1; k4<64; ++k4){
      z = z4p[k4]; w = w4p[k4];
      zs = __fadd_rn(zs, __fmul_rn(z.x, z.x)); ss = __fadd_rn(ss, __fmul_rn(z.x, w.x));
      zs = __fadd_rn(zs, __fmul_rn(z.y, z.y)); ss = __fadd_rn(ss, __fmul_rn(z.y, w.y));
      zs = __fadd_rn(zs, __fmul_rn(z.z, z.z)); ss = __fadd_rn(ss, __fmul_rn(z.z, w.z));
      zs = __fadd_rn(zs, __fmul_rn(z.w, z.w)); ss = __fadd_rn(ss, __fmul_rn(z.w, w.w));
    }
    {
      const float v = __fadd_rn(__fsub_rn(zs, __fmul_rn(2.0f, ss)), wsq[idx0]);
      minmerge(bv, bi, v, idx0);
    }
    /* remaining candidates: r11 dot sequence, float4-loaded in order */
    for (int i=1; i<sel; ++i){
      const int idx = cand[(size_t)row*CEXP + i];
      const float4* wp = (const float4*)(W + (size_t)idx*DD);
      float s2 = 0.f;
      for (int k4=0; k4<64; ++k4){
        float4 zz = z4p[k4], ww = wp[k4];
        s2 = __fadd_rn(s2, __fmul_rn(zz.x, ww.x));
        s2 = __fadd_rn(s2, __fmul_rn(zz.y, ww.y));
        s2 = __fadd_rn(s2, __fmul_rn(zz.z, ww.z));
        s2 = __fadd_rn(s2, __fmul_rn(zz.w, ww.w));
      }
      const float v = __fadd_rn(__fsub_rn(zs, __fmul_rn(2.0f, s2)), wsq[idx]);
      minmerge(bv, bi, v, idx);
    }
  }
  rowcode[row] = bi;
  out[O_IDX + row] = (float)bi;
  atomicAdd(&cnt[bi], 1);
}

/* exclusive prefix sum over 1024 counts -> offs (with sentinel), pos */
__global__ __launch_bounds__(1024,1) void vq_prefix_kernel(
    const int* __restrict__ cnt, int* __restrict__ offs, int* __restrict__ pos)
{
  __shared__ int s[1024];
  const int tid = threadIdx.x;
  const int c = cnt[tid];
  s[tid] = c;
  __syncthreads();
  #pragma unroll
  for (int off=1; off<1024; off<<=1){
    int v = s[tid];
    int a = (tid >= off) ? s[tid-off] : 0;
    __syncthreads();
    s[tid] = v + a;
    __syncthreads();
  }
  const int ex = s[tid] - c;
  offs[tid] = ex;
  pos[tid]  = ex;
  if (tid == 1023) offs[1024] = NROWS;
}

/* bucket row ids by code */
__global__ __launch_bounds__(256,1) void vq_scatter_kernel(
    const int* __restrict__ rowcode, int* __restrict__ pos, int* __restrict__ bucket)
{
  const int r = blockIdx.x*256 + threadIdx.x;
  const int k = rowcode[r];
  const int slot = atomicAdd(&pos[k], 1);
  bucket[slot] = r;
}

/* chunksum + fused zq epilogue: 16-entry chunks, 1024 blocks x 4 waves
   (16 waves/CU). st flush at code boundaries; zq_st write + dist partials. */
__global__ __launch_bounds__(256,4) void vq_chunksum_kernel(
    const float* __restrict__ ze, const float* __restrict__ W,
    const int* __restrict__ bucket, const int* __restrict__ offs,
    float* __restrict__ st, float* __restrict__ out,
    float* __restrict__ dist_part)
{
  __shared__ int offsS[1025];
  __shared__ float dps[4];
  const int tid = threadIdx.x;
  for (int i=tid; i<1025; i+=256) offsS[i] = offs[i];
  __syncthreads();

  const int wv = tid >> 6, lane = tid & 63;
  const int j0 = (blockIdx.x*4 + wv)*16;

  int r, k;
  {
    const int j = j0 + (lane & 15);
    r = bucket[j];
    int lo = 0, hi = 1024;
    #pragma unroll
    for (int it=0; it<10; ++it){
      int mid = (lo + hi) >> 1;
      if (offsS[mid] <= j) lo = mid; else hi = mid;
    }
    k = lo;
  }

  float4 acc = {0.f,0.f,0.f,0.f};
  float distp = 0.f;
  int kprev = __shfl(k, 0);
  #pragma unroll
  for (int g=0; g<2; ++g){
    float4 v[8]; int rk[8]; int rr[8];
    #pragma unroll
    for (int i=0;i<8;i++){
      rr[i] = __shfl(r, g*8+i);
      rk[i] = __shfl(k, g*8+i);
      v[i] = *(const float4*)&ze[(size_t)rr[i]*DD + lane*4];
    }
    #pragma unroll
    for (int i=0;i<8;i++){
      if (rk[i] != kprev){
        atomicAdd(&st[(size_t)kprev*DD + lane*4 + 0], acc.x);
        atomicAdd(&st[(size_t)kprev*DD + lane*4 + 1], acc.y);
        atomicAdd(&st[(size_t)kprev*DD + lane*4 + 2], acc.z);
        atomicAdd(&st[(size_t)kprev*DD + lane*4 + 3], acc.w);
        acc = (float4){0.f,0.f,0.f,0.f};
        kprev = rk[i];
      }
      acc.x += v[i].x; acc.y += v[i].y; acc.z += v[i].z; acc.w += v[i].w;
      /* fused zq epilogue for this row (reference formula) */
      float4 w4 = *(const float4*)&W[(size_t)rk[i]*DD + lane*4];
      float4 o;
      o.x = v[i].x + (w4.x - v[i].x);
      o.y = v[i].y + (w4.y - v[i].y);
      o.z = v[i].z + (w4.z - v[i].z);
      o.w = v[i].w + (w4.w - v[i].w);
      *(float4*)&out[O_ZQ + (size_t)rr[i]*DD + lane*4] = o;
      float dx;
      dx = w4.x - v[i].x; distp += dx*dx;
      dx = w4.y - v[i].y; distp += dx*dx;
      dx = w4.z - v[i].z; distp += dx*dx;
      dx = w4.w - v[i].w; distp += dx*dx;
    }
  }
  atomicAdd(&st[(size_t)kprev*DD + lane*4 + 0], acc.x);
  atomicAdd(&st[(size_t)kprev*DD + lane*4 + 1], acc.y);
  atomicAdd(&st[(size_t)kprev*DD + lane*4 + 2], acc.z);
  atomicAdd(&st[(size_t)kprev*DD + lane*4 + 3], acc.w);

  /* dist: wave reduce -> block partial (no global atomics) */
  #pragma unroll
  for (int m=1; m<64; m<<=1) distp += __shfl_xor(distp, m);
  if (lane == 0) dps[wv] = distp;
  __syncthreads();
  if (tid == 0) dist_part[blockIdx.x] = dps[0]+dps[1]+dps[2]+dps[3];
}

/* EMA tail: mt_new, embedW_new, Nt_new; block 0 also finalizes dist */
__global__ __launch_bounds__(256,1) void vq_tail_kernel(
    const float* __restrict__ mt, const float* __restrict__ Nt,
    const float* __restrict__ st, const int* __restrict__ cnt,
    const float* __restrict__ dist_part, float* __restrict__ out)
{
  const float G   = 0.99f;
  const float OMG = (float)(1.0 - 0.99);
  const int i = blockIdx.x*256 + threadIdx.x;   /* 0..KD-1 */
  const int k = i >> 8;
  const float ntn = __fadd_rn(__fmul_rn(G, Nt[k]), __fmul_rn(OMG, (float)cnt[k]));
  const float mtn = __fadd_rn(__fmul_rn(G, mt[i]), __fmul_rn(OMG, st[i]));
  out[O_MT  + i] = mtn;
  out[O_EMB + i] = mtn / ntn;
  if ((i & 255) == 0) out[O_NT + k] = ntn;

  if (blockIdx.x == 0){
    __shared__ float ds[4];
    const int tid = threadIdx.x;
    float s = 0.f;
    #pragma unroll
    for (int q=0; q<4; ++q) s += dist_part[tid + q*256];
    #pragma unroll
    for (int m=1; m<64; m<<=1) s += __shfl_xor(s, m);
    if ((tid & 63) == 0) ds[tid >> 6] = s;
    __syncthreads();
    if (tid == 0) out[O_DIST] = (ds[0]+ds[1]+ds[2]+ds[3]) * (1.0f/16777216.0f);
  }
}

extern "C" void kernel_launch(void* const* d_in, const int* in_sizes, int n_in,
                              void* d_out, int out_size, void* d_ws, size_t ws_size,
                              hipStream_t stream){
  const float* ze = (const float*)d_in[0];
  const float* W  = (const float*)d_in[1];
  const float* mt = (const float*)d_in[2];
  const float* Nt = (const float*)d_in[3];
  float* out  = (float*)d_out;
  float* ws   = (float*)d_ws;
  float*  wsq  = ws + WS_WSQ;
  bf16x8* wpk  = (bf16x8*)(ws + WS_WPK);
  int*    rowc = (int*)(ws + WS_ROWC);
  int*    buck = (int*)(ws + WS_BUCK);
  int*    offs = (int*)(ws + WS_OFFS);
  int*    pos  = (int*)(ws + WS_POS);
  int*    cnt  = (int*)(ws + WS_CNT);
  float*  st   = ws + WS_ST;
  unsigned short* cand = (unsigned short*)(ws + WS_CAND);
  unsigned short* selw = (unsigned short*)(ws + WS_SEL);
  float*  distp = ws + WS_DISTP;

  /* zero cnt + legacy dist slot + st in one shot (contiguous) */
  hipMemsetAsync((void*)(ws + WS_CNT), 0, (size_t)(KC + 4 + KD)*sizeof(float), stream);
  /* zero dist partials (1024 blocks now) */
  hipMemsetAsync((void*)(ws + WS_DISTP), 0, 1024*sizeof(float), stream);
  vq_prep_kernel    <<<KC/4,        256, 0, stream>>>(W, wsq, wpk);
  vq_screen_kernel  <<<NROWS/BROWS, 512, 0, stream>>>(ze, wpk, wsq, cand, selw);
  vq_decide_kernel  <<<NROWS/256,   256, 0, stream>>>(ze, W, wsq, cand, selw, rowc, cnt, out);
  vq_prefix_kernel  <<<1,          1024, 0, stream>>>(cnt, offs, pos);
  vq_scatter_kernel <<<NROWS/256,   256, 0, stream>>>(rowc, pos, buck);
  vq_chunksum_kernel<<<NROWS/64,    256, 0, stream>>>(ze, W, buck, offs, st, out, distp);
  vq_tail_kernel    <<<KD/256,      256, 0, stream>>>(mt, Nt, st, cnt, distp, out);
}